// Round 11
// baseline (548.825 us; speedup 1.0000x reference)
//
#include <hip/hip_runtime.h>
#include <math.h>

// Problem constants
#define NN 118   // nodes
#define EE 372   // edges
#define GG 2048  // B*T
#define DD 128   // hidden
#define TT 256   // seq len
#define BB 8     // batch
#define FD 512   // 4*D

// LDS stride for bf16 matrices (rows 16B-aligned, 2-way-max bank aliasing)
#define XS 136

typedef short bf16x8 __attribute__((ext_vector_type(8)));
typedef float f32x4  __attribute__((ext_vector_type(4)));
typedef _Float16 f16x2 __attribute__((ext_vector_type(2)));

__device__ __forceinline__ float frcp_(float x) { return __builtin_amdgcn_rcpf(x); }
__device__ __forceinline__ float sig_f(float x) { return frcp_(1.0f + __expf(-x)); }
__device__ __forceinline__ float tanh_f(float x) { return 1.0f - 2.0f * frcp_(__expf(2.0f * x) + 1.0f); }
__device__ __forceinline__ float silu_f(float x) { return x * frcp_(1.0f + __expf(-x)); }
__device__ __forceinline__ float siluf_(float x) { return x / (1.0f + expf(-x)); }

// f16-pair dot with fp32 accumulate (v_dot2_f32_f16); scalar fallback.
__device__ __forceinline__ float fdot2_(unsigned int a, unsigned int b, float c) {
#if defined(__has_builtin) && __has_builtin(__builtin_amdgcn_fdot2)
    return __builtin_amdgcn_fdot2(__builtin_bit_cast(f16x2, a),
                                  __builtin_bit_cast(f16x2, b), c, false);
#else
    f16x2 x = __builtin_bit_cast(f16x2, a), y = __builtin_bit_cast(f16x2, b);
    return c + (float)x[0] * (float)y[0] + (float)x[1] * (float)y[1];
#endif
}

// Barrier draining only LDS ops (lgkmcnt), not vmcnt: global stores stay
// fire-and-forget, prefetch loads stay in flight. Safe: all cross-thread data
// flows through LDS (global->VGPR uses get compiler vmcnt waits).
__device__ __forceinline__ void bar_lds() {
    asm volatile("s_waitcnt lgkmcnt(0)\n\ts_barrier" ::: "memory");
}

__device__ __forceinline__ unsigned short f2bf(float x) {
    unsigned int u = __float_as_uint(x);
    unsigned int r = (u + 0x7fffu + ((u >> 16) & 1u)) >> 16;
    return (unsigned short)r;
}
__device__ __forceinline__ float bf2f(unsigned short b) {
    return __uint_as_float(((unsigned int)b) << 16);
}

// ---------------------------------------------------------------------------
// setup: ALL weight-prep fused into one launch (449 blocks x 512 thr):
//   [0,32)    convw W2  -> Wt2g      [32,64)   convw W3  -> Wt3g
//   [64,128)  convh Whh0-> Wc0       [128,192) convh Whh1-> Wc1
//   [192,320) transpose Wih0 -> WT0  [320,448) transpose Wih1 -> WT1
//   448       prep (adjacency + fused biases)
// (round-9 verified version, byte-identical)
// ---------------------------------------------------------------------------
__global__ __launch_bounds__(512) void setup_kernel(
    const int* __restrict__ ei,
    const float* __restrict__ bih0, const float* __restrict__ bhh0,
    const float* __restrict__ bih1, const float* __restrict__ bhh1,
    float* __restrict__ bias0, float* __restrict__ bias1,
    unsigned short* __restrict__ AbG,
    const float* __restrict__ W2, unsigned short* __restrict__ Wt2g,
    const float* __restrict__ W3, unsigned short* __restrict__ Wt3g,
    const float* __restrict__ Whh0, unsigned int* __restrict__ Wc0,
    const float* __restrict__ Whh1, unsigned int* __restrict__ Wc1,
    const float* __restrict__ Wih0, float* __restrict__ WT0,
    const float* __restrict__ Wih1, float* __restrict__ WT1) {
    int blk = blockIdx.x, tid = threadIdx.x;
    if (blk < 64) {
        // convw: W (K=128 x N=128, fp32) -> bf16 [n][k]
        const float* W = (blk < 32) ? W2 : W3;
        unsigned short* out = (blk < 32) ? Wt2g : Wt3g;
        int i = (blk & 31) * 512 + tid;  // 16384 total
        int n = i >> 7, k = i & 127;
        out[i] = f2bf(W[k * DD + n]);
        return;
    }
    if (blk < 192) {
        // convh: W[512][128] (rows r=g*128+d) -> quad-K-split f16 pairs
        // (ROUND-3 LAYOUT, verified): out[(g*16+m)*512 + ((d<<2)|q)]
        const float* W = (blk < 128) ? Whh0 : Whh1;
        unsigned int* out = (blk < 128) ? Wc0 : Wc1;
        int i = ((blk - 64) & 63) * 512 + tid;  // 32768 total
        int pair = i >> 9, jj = i & 511;        // pair = g*16+m, jj = (d<<2)|q
        int g = pair >> 4, m = pair & 15;
        int d = jj >> 2, q = jj & 3;
        const float* row = W + (size_t)(g * 128 + d) * 128 + q * 32 + 2 * m;
        float a = row[0], b = row[1];
        unsigned short lo = __builtin_bit_cast(unsigned short, (_Float16)a);
        unsigned short hi = __builtin_bit_cast(unsigned short, (_Float16)b);
        out[i] = (unsigned int)lo | ((unsigned int)hi << 16);
        return;
    }
    if (blk < 448) {
        // transpose: Wih (512x128) -> WT [k=128][j=512]
        const float* in = (blk < 320) ? Wih0 : Wih1;
        float* out = (blk < 320) ? WT0 : WT1;
        int idx = ((blk - 192) & 127) * 512 + tid;  // 65536 total
        int j = idx >> 7, k = idx & 127;
        out[k * FD + j] = in[idx];
        return;
    }
    // ------------------- prep (block 448) -------------------
    __shared__ int sflag;
    __shared__ int ssrc[EE], sdst[EE];
    __shared__ int scount[NN];
    __shared__ float sinv[NN];
    __shared__ float Adense[NN * NN];  // 55.7 KB
    if (tid == 0) sflag = 0;
    __syncthreads();
    // int64-vs-int32 layout detect (values < 118 -> high words zero if int64)
    for (int i = tid; i < 2 * EE; i += blockDim.x)
        if ((i & 1) && ei[i] != 0) atomicOr(&sflag, 1);
    __syncthreads();
    bool m64 = (sflag == 0);
    for (int e = tid; e < EE; e += blockDim.x) {
        int s, d;
        if (m64) { s = ei[2 * e]; d = ei[2 * EE + 2 * e]; }
        else     { s = ei[e];     d = ei[EE + e]; }
        s = min(max(s, 0), NN - 1); d = min(max(d, 0), NN - 1);
        ssrc[e] = s; sdst[e] = d;
    }
    for (int n = tid; n < NN; n += blockDim.x) scount[n] = 0;
    for (int i = tid; i < NN * NN; i += blockDim.x) Adense[i] = 0.0f;
    __syncthreads();
    for (int e = tid; e < EE; e += blockDim.x) atomicAdd(&scount[sdst[e]], 1);
    __syncthreads();
    for (int n = tid; n < NN; n += blockDim.x) {
        float deg = 1.0f + (float)scount[n];
        sinv[n] = rsqrtf(deg);
        Adense[n * NN + n] = 1.0f / deg;   // self term h*(1/deg)
    }
    __syncthreads();
    for (int e = tid; e < EE; e += blockDim.x)
        atomicAdd(&Adense[sdst[e] * NN + ssrc[e]], sinv[ssrc[e]] * sinv[sdst[e]]);
    __syncthreads();
    for (int i = tid; i < 128 * 128; i += blockDim.x) {
        int r = i >> 7, c = i & 127;
        AbG[i] = (r < NN && c < NN) ? f2bf(Adense[r * NN + c]) : (unsigned short)0;
    }
    for (int j = tid; j < FD; j += blockDim.x) {
        bias0[j] = bih0[j] + bhh0[j];
        bias1[j] = bih1[j] + bhh1[j];
    }
}

// ---------------------------------------------------------------------------
// GCN building blocks (round-3 LDS-staged versions, verified)
// ---------------------------------------------------------------------------
__device__ __forceinline__ void load_m(const unsigned short* __restrict__ src,
                                       unsigned short* __restrict__ dst, int tid) {
    const uint4* s4 = (const uint4*)src;  // 2048 chunks of 16B (8 bf16)
    for (int c = tid; c < 2048; c += 512) {
        int r = c >> 4, k8 = (c & 15) * 8;
        uint4 v = s4[c];
        *(uint4*)(dst + r * XS + k8) = v;
    }
}

// mm1: hS[n=dout][m=node] = (xb[m][k] @ wt[n][k]) packed bf16
__device__ __forceinline__ void mm_xw(const unsigned short* __restrict__ xb,
                                      const unsigned short* __restrict__ wt,
                                      unsigned short* __restrict__ hS, int tid) {
    int lane = tid & 63, w = tid >> 6;
    int lm = lane & 15, lq = lane >> 4;
    int wm = (w & 1) * 64, wn = (w >> 1) * 32;
    f32x4 acc[4][2];
#pragma unroll
    for (int mt = 0; mt < 4; ++mt)
#pragma unroll
        for (int nt = 0; nt < 2; ++nt) acc[mt][nt] = (f32x4){0.f, 0.f, 0.f, 0.f};
#pragma unroll
    for (int kb = 0; kb < 4; ++kb) {
        int ko = kb * 32 + lq * 8;
        bf16x8 b0 = *(const bf16x8*)(wt + (wn + lm) * XS + ko);
        bf16x8 b1 = *(const bf16x8*)(wt + (wn + 16 + lm) * XS + ko);
#pragma unroll
        for (int mt = 0; mt < 4; ++mt) {
            bf16x8 af = *(const bf16x8*)(xb + (wm + mt * 16 + lm) * XS + ko);
            acc[mt][0] = __builtin_amdgcn_mfma_f32_16x16x32_bf16(af, b0, acc[mt][0], 0, 0, 0);
            acc[mt][1] = __builtin_amdgcn_mfma_f32_16x16x32_bf16(af, b1, acc[mt][1], 0, 0, 0);
        }
    }
#pragma unroll
    for (int mt = 0; mt < 4; ++mt)
#pragma unroll
        for (int nt = 0; nt < 2; ++nt) {
            f32x4 a = acc[mt][nt];
            ushort4 pk;
            pk.x = f2bf(a[0]); pk.y = f2bf(a[1]); pk.z = f2bf(a[2]); pk.w = f2bf(a[3]);
            *(ushort4*)(hS + (wn + nt * 16 + lm) * XS + wm + mt * 16 + lq * 4) = pk;
        }
}

// mm2: xb[m=node][n=d] = silu(Ab[m][k] @ hS[n][k] + bias[n]) bf16
__device__ __forceinline__ void mm_agg(const unsigned short* __restrict__ Ab,
                                       const unsigned short* __restrict__ hS,
                                       unsigned short* __restrict__ xb,
                                       float bn0, float bn1, int tid) {
    int lane = tid & 63, w = tid >> 6;
    int lm = lane & 15, lq = lane >> 4;
    int wm = (w & 1) * 64, wn = (w >> 1) * 32;
    f32x4 acc[4][2];
#pragma unroll
    for (int mt = 0; mt < 4; ++mt)
#pragma unroll
        for (int nt = 0; nt < 2; ++nt) acc[mt][nt] = (f32x4){0.f, 0.f, 0.f, 0.f};
#pragma unroll
    for (int kb = 0; kb < 4; ++kb) {
        int ko = kb * 32 + lq * 8;
        bf16x8 b0 = *(const bf16x8*)(hS + (wn + lm) * XS + ko);
        bf16x8 b1 = *(const bf16x8*)(hS + (wn + 16 + lm) * XS + ko);
#pragma unroll
        for (int mt = 0; mt < 4; ++mt) {
            bf16x8 af = *(const bf16x8*)(Ab + (wm + mt * 16 + lm) * XS + ko);
            acc[mt][0] = __builtin_amdgcn_mfma_f32_16x16x32_bf16(af, b0, acc[mt][0], 0, 0, 0);
            acc[mt][1] = __builtin_amdgcn_mfma_f32_16x16x32_bf16(af, b1, acc[mt][1], 0, 0, 0);
        }
    }
#pragma unroll
    for (int mt = 0; mt < 4; ++mt)
#pragma unroll
        for (int nt = 0; nt < 2; ++nt) {
            float bn = nt ? bn1 : bn0;
            int col = wn + nt * 16 + lm;
#pragma unroll
            for (int i = 0; i < 4; ++i) {
                float v = silu_f(acc[mt][nt][i] + bn);
                xb[(wm + mt * 16 + lq * 4 + i) * XS + col] = f2bf(v);
            }
        }
}

// ---------------------------------------------------------------------------
// gcn: round-9 structure (2 graphs/block, LDS-staged operands, verified) PLUS
// fused proj#1: the graph embedding (in LDS meanS) is projected through WT0
// (+bias0) by all 512 threads and written straight to inp -- deletes the
// proj#1 dispatch and the emb global round-trip. Arithmetic identical to
// proj_kernel. (Round-10's failure is attributed to the fscan ride-along:
// its absmax matched round-6 exactly, which predates this fusion.)
// ---------------------------------------------------------------------------
__global__ __launch_bounds__(512) void gcn_kernel(
    const float* __restrict__ xg, const float* __restrict__ scale, const float* __restrict__ shift,
    const float* __restrict__ W1, const float* __restrict__ b1,
    const float* __restrict__ b2, const float* __restrict__ b3,
    const unsigned short* __restrict__ AbG,
    const unsigned short* __restrict__ Wt2g, const unsigned short* __restrict__ Wt3g,
    const float* __restrict__ WT0, const float* __restrict__ bias0,
    float* __restrict__ inp) {
    extern __shared__ char smem[];
    unsigned short* xb = (unsigned short*)smem;              // 34816 B  [node][d]
    unsigned short* hS = (unsigned short*)(smem + 34816);    // 34816 B  [d][node]
    unsigned short* Ab = (unsigned short*)(smem + 69632);    // 34816 B  [dst][src]
    unsigned short* wt = (unsigned short*)(smem + 104448);   // 34816 B  [dout][din]
    float* xinL  = (float*)(smem + 139264);                  // 354 f
    float* meanS = (float*)(smem + 140688);                  // 512 f (end 142736)
    int tid = threadIdx.x;
    int lane = tid & 63, w = tid >> 6;

    for (int i = tid; i < 2176; i += 512) ((uint4*)hS)[i] = (uint4){0, 0, 0, 0};
    for (int i = tid; i < 170; i += 512) ((uint4*)(xb + NN * XS))[i] = (uint4){0, 0, 0, 0};
    float s0 = scale[0], s1 = scale[1], s2 = scale[2];
    float t0 = shift[0], t1 = shift[1], t2 = shift[2];
    load_m(AbG, Ab, tid);
    int lm = lane & 15;
    int wn = (w >> 1) * 32;
    int n0 = wn + lm, n1 = wn + 16 + lm;
    float b1a = b1[n0], b1b = b1[n1];
    float b2a = b2[n0], b2b = b2[n1];
    float b3a = b3[n0], b3b = b3[n1];
    float bp0 = bias0[tid];
    int dd = lane * 2;
    float2 w10 = *(const float2*)(W1 + dd);
    float2 w11 = *(const float2*)(W1 + DD + dd);
    float2 w12 = *(const float2*)(W1 + 2 * DD + dd);
    for (int gg = 0; gg < 2; ++gg) {
        int g = blockIdx.x * 2 + gg;
        const float* xrow = xg + (size_t)g * (NN * 3);
        for (int i = tid; i < NN * 3; i += 512) {
            int f = i % 3;
            float sc = (f == 0) ? s0 : ((f == 1) ? s1 : s2);
            float sf = (f == 0) ? t0 : ((f == 1) ? t1 : t2);
            xinL[i] = xrow[i] * sc + sf;
        }
        load_m(Wt2g, wt, tid);
        bar_lds();
        for (int k = 0; k < 15; ++k) {
            int n = w + 8 * k;
            if (n >= NN) break;
            float x0 = xinL[n * 3], x1 = xinL[n * 3 + 1], x2 = xinL[n * 3 + 2];
            hS[dd * XS + n]       = f2bf(x0 * w10.x + x1 * w11.x + x2 * w12.x);
            hS[(dd + 1) * XS + n] = f2bf(x0 * w10.y + x1 * w11.y + x2 * w12.y);
        }
        bar_lds();
        mm_agg(Ab, hS, xb, b1a, b1b, tid);   // x1
        bar_lds();
        mm_xw(xb, wt, hS, tid);              // h2
        bar_lds();
        load_m(Wt3g, wt, tid);
        mm_agg(Ab, hS, xb, b2a, b2b, tid);   // x2
        bar_lds();
        mm_xw(xb, wt, hS, tid);              // h3
        bar_lds();
        mm_agg(Ab, hS, xb, b3a, b3b, tid);   // x3
        bar_lds();
        {
            int d = tid & 127, part = tid >> 7;
            int a0 = part * 30;
            int a1 = (a0 + 30 < NN) ? (a0 + 30) : NN;
            float s = 0.f;
            for (int n = a0; n < a1; ++n) s += bf2f(xb[n * XS + d]);
            meanS[part * 128 + d] = s;
        }
        bar_lds();
        if (tid < 128) {
            float s = meanS[tid] + meanS[128 + tid] + meanS[256 + tid] + meanS[384 + tid];
            meanS[tid] = s * (1.0f / (float)NN);   // emb stays in LDS
        }
        bar_lds();
        {   // fused proj#1: inp[g][j] = bias0[j] + sum_k emb[k]*WT0[k][j]
            float acc = bp0;
            const float* wt0 = WT0 + tid;
#pragma unroll 8
            for (int k = 0; k < DD; ++k) acc += meanS[k] * wt0[(size_t)k * FD];
            inp[(size_t)g * FD + tid] = acc;
        }
        bar_lds();
    }
}

// ---------------------------------------------------------------------------
// proj: dst[g][j] = bias[j] + sum_k src[g][k] * WT[k][j]   (layer-1 input)
// ---------------------------------------------------------------------------
__global__ __launch_bounds__(512) void proj_kernel(const float* __restrict__ src,
                                                   const float* __restrict__ WT,
                                                   const float* __restrict__ bias,
                                                   float* __restrict__ dst) {
    __shared__ __align__(16) float eL[DD];
    int g = blockIdx.x, tid = threadIdx.x;
    if (tid < DD) eL[tid] = src[(size_t)g * DD + tid];
    __syncthreads();
    float acc = bias[tid];
    const float* wt = WT + tid;
#pragma unroll 8
    for (int k = 0; k < DD; ++k) acc += eL[k] * wt[(size_t)k * FD];
    dst[(size_t)g * FD + tid] = acc;
}

// ---------------------------------------------------------------------------
// LSTM scan v3: QUAD-K-SPLIT (round-3 verified, byte-identical). Thread
// j = (d = j>>2, q = j&3); quad lane q is BOTH the owned gate index AND the
// K-quarter. Each thread reads its 64 B quarter of h (4 x ds_read_b128),
// computes partials for ALL 4 gates over that quarter, 2-step DPP quad
// butterfly (0xB1, 0x4E), 3 cndmask select own gate, branchless activation,
// quad broadcast (0x00/0x55/0xAA/0xFF), redundant c/h update. One barrier
// per step, h double-buffered (512 B LDS).
// ---------------------------------------------------------------------------
__global__ __launch_bounds__(512, 1) void scan_kernel(
    const float* __restrict__ inp,          // [B][T][512] gate-major (bias incl)
    const unsigned int* __restrict__ Wc,    // [pair=g*16+m][j=(d<<2)|q] f16 pairs
    float* __restrict__ hout, int full) {
    __shared__ __align__(16) unsigned short hB[2][DD];  // h as f16, double-buffered
    int b = blockIdx.x, j = threadIdx.x;
    int d = j >> 2, q = j & 3;
    unsigned int wreg[4][16];  // [gate][pair], K-quarter q only
#pragma unroll
    for (int g = 0; g < 4; ++g)
#pragma unroll
        for (int m = 0; m < 16; ++m)
            wreg[g][m] = Wc[(g * 16 + m) * 512 + j];
    // pin: asm-defined values cannot be rematerialized into the loop
#pragma unroll
    for (int g = 0; g < 4; ++g)
#pragma unroll
        for (int m = 0; m < 16; ++m)
            asm volatile("" : "+v"(wreg[g][m]));
    if (j < 128) ((unsigned int*)hB)[j] = 0u;  // zero both buffers (512 B)
    const float* ib = inp + (size_t)b * TT * FD;
    float* hb_ = hout + (size_t)b * (full ? TT * DD : DD);
    int poff = q * DD + d;
    // branchless activation: act = sig(pre*m1)*m1 + c1  (q==2 -> tanh)
    float m1  = (q == 2) ? 2.0f : 1.0f;
    float nm1 = -m1;
    float c1  = 1.0f - m1;
    bool b0 = (q & 1) != 0, b1s = (q & 2) != 0;  // own-gate select bits
    float creg = 0.f;
    float xg0 = ib[poff], xg1 = ib[FD + poff];  // prefetch depth 2
    int p = 0;
    bar_lds();
    for (int t = 0; t < TT; ++t) {
        float xg2 = (t + 2 < TT) ? ib[(size_t)(t + 2) * FD + poff] : 0.f;
        // each quad lane reads its own 64 B K-quarter (4 chunks)
        const uint4* h4 = (const uint4*)(hB[p]) + q * 4;
        float p0 = 0.f, p1 = 0.f, p2 = 0.f, p3 = 0.f;
#pragma unroll
        for (int c = 0; c < 4; ++c) {
            uint4 hv = h4[c];
            p0 = fdot2_(wreg[0][4 * c + 0], hv.x, p0);
            p1 = fdot2_(wreg[1][4 * c + 0], hv.x, p1);
            p2 = fdot2_(wreg[2][4 * c + 0], hv.x, p2);
            p3 = fdot2_(wreg[3][4 * c + 0], hv.x, p3);
            p0 = fdot2_(wreg[0][4 * c + 1], hv.y, p0);
            p1 = fdot2_(wreg[1][4 * c + 1], hv.y, p1);
            p2 = fdot2_(wreg[2][4 * c + 1], hv.y, p2);
            p3 = fdot2_(wreg[3][4 * c + 1], hv.y, p3);
            p0 = fdot2_(wreg[0][4 * c + 2], hv.z, p0);
            p1 = fdot2_(wreg[1][4 * c + 2], hv.z, p1);
            p2 = fdot2_(wreg[2][4 * c + 2], hv.z, p2);
            p3 = fdot2_(wreg[3][4 * c + 2], hv.z, p3);
            p0 = fdot2_(wreg[0][4 * c + 3], hv.w, p0);
            p1 = fdot2_(wreg[1][4 * c + 3], hv.w, p1);
            p2 = fdot2_(wreg[2][4 * c + 3], hv.w, p2);
            p3 = fdot2_(wreg[3][4 * c + 3], hv.w, p3);
        }
        // quad butterfly: sum the 4 K-quarter partials per gate
#define DPPADD(pv, ctrl) { \
            float _t = __int_as_float(__builtin_amdgcn_update_dpp( \
                0, __float_as_int(pv), ctrl, 0xF, 0xF, true)); \
            pv += _t; }
        DPPADD(p0, 0xB1) DPPADD(p1, 0xB1) DPPADD(p2, 0xB1) DPPADD(p3, 0xB1)
        DPPADD(p0, 0x4E) DPPADD(p1, 0x4E) DPPADD(p2, 0x4E) DPPADD(p3, 0x4E)
#undef DPPADD
        // select own gate (q) and activate
        float s01 = b0 ? p1 : p0;
        float s23 = b0 ? p3 : p2;
        float own = b1s ? s23 : s01;
        float pre = own + xg0;
        float act = frcp_(1.0f + __expf(pre * nm1)) * m1 + c1;
        // quad broadcast: lane k of each quad -> all quad lanes (VALU DPP)
        int ai = __float_as_int(act);
        float iv = __int_as_float(__builtin_amdgcn_update_dpp(0, ai, 0x00, 0xF, 0xF, true));
        float fv = __int_as_float(__builtin_amdgcn_update_dpp(0, ai, 0x55, 0xF, 0xF, true));
        float gv = __int_as_float(__builtin_amdgcn_update_dpp(0, ai, 0xAA, 0xF, 0xF, true));
        float ov = __int_as_float(__builtin_amdgcn_update_dpp(0, ai, 0xFF, 0xF, 0xF, true));
        float cn = fv * creg + iv * gv;
        creg = cn;
        float hn = ov * tanh_f(cn);
        if (q == 0) {
            ((_Float16*)hB[p ^ 1])[d] = (_Float16)hn;
            if (full) {
                hb_[t * DD + d] = hn;                 // fire-and-forget
            } else if (t == TT - 1) {
                hb_[d] = hn;
            }
        }
        xg0 = xg1; xg1 = xg2;
        p ^= 1;
        bar_lds();
    }
}

// ---------------------------------------------------------------------------
// head MLP on final hidden state. 1 block.
// ---------------------------------------------------------------------------
__global__ void head_kernel(const float* __restrict__ hfin,
                            const float* __restrict__ hW1, const float* __restrict__ hb1,
                            const float* __restrict__ hW2, const float* __restrict__ hb2,
                            const float* __restrict__ hW3, const float* __restrict__ hb3,
                            float* __restrict__ out) {
    __shared__ float fh[BB * DD];
    __shared__ float y1[BB * DD];
    __shared__ float y2[BB * 64];
    int tid = threadIdx.x;
    for (int i = tid; i < BB * DD; i += 256) fh[i] = hfin[i];
    __syncthreads();
    for (int i = tid; i < BB * DD; i += 256) {
        int bb = i >> 7, jj = i & 127;
        float acc = hb1[jj];
        for (int k = 0; k < DD; ++k) acc += fh[(bb << 7) + k] * hW1[(k << 7) + jj];
        y1[i] = siluf_(acc);
    }
    __syncthreads();
    for (int i = tid; i < BB * 64; i += 256) {
        int bb = i >> 6, jj = i & 63;
        float acc = hb2[jj];
        for (int k = 0; k < DD; ++k) acc += y1[(bb << 7) + k] * hW2[(k << 6) + jj];
        y2[i] = siluf_(acc);
    }
    __syncthreads();
    if (tid < BB * 2) {
        int bb = tid >> 1, m = tid & 1;
        float acc = hb3[m];
        for (int k = 0; k < 64; ++k) acc += y2[(bb << 6) + k] * hW3[k * 2 + m];
        float sp = fmaxf(acc, 0.f) + log1pf(expf(-fabsf(acc)));
        out[tid] = sp + 1e-6f;
    }
}

// ---------------------------------------------------------------------------
extern "C" void kernel_launch(void* const* d_in, const int* in_sizes, int n_in,
                              void* d_out, int out_size, void* d_ws, size_t ws_size,
                              hipStream_t stream) {
    const float* snap  = (const float*)d_in[0];
    const int*   edges = (const int*)d_in[1];
    const float* scale = (const float*)d_in[2];
    const float* shift = (const float*)d_in[3];
    const float* W1 = (const float*)d_in[4];
    const float* b1 = (const float*)d_in[5];
    const float* W2 = (const float*)d_in[6];
    const float* b2 = (const float*)d_in[7];
    const float* W3 = (const float*)d_in[8];
    const float* b3 = (const float*)d_in[9];
    const float* Wih0 = (const float*)d_in[10];
    const float* Whh0 = (const float*)d_in[11];
    const float* bih0 = (const float*)d_in[12];
    const float* bhh0 = (const float*)d_in[13];
    const float* Wih1 = (const float*)d_in[14];
    const float* Whh1 = (const float*)d_in[15];
    const float* bih1 = (const float*)d_in[16];
    const float* bhh1 = (const float*)d_in[17];
    const float* hW1 = (const float*)d_in[18];
    const float* hb1 = (const float*)d_in[19];
    const float* hW2 = (const float*)d_in[20];
    const float* hb2 = (const float*)d_in[21];
    const float* hW3 = (const float*)d_in[22];
    const float* hb3 = (const float*)d_in[23];

    // workspace carve (float indices); ~7.2 MB  (round-9 layout, verified)
    float* ws = (float*)d_ws;
    float* bias0 = ws + 0;                        // 512
    float* bias1 = ws + 512;                      // 512
    unsigned short* AbG  = (unsigned short*)(ws + 1024);   // 8192 f
    unsigned short* Wt2g = (unsigned short*)(ws + 9216);   // 8192 f
    unsigned short* Wt3g = (unsigned short*)(ws + 17408);  // 8192 f
    float* WT0 = ws + 25600;                      // 65536
    float* WT1 = ws + 91136;                      // 65536
    unsigned int* Wc0 = (unsigned int*)(ws + 156672);      // 32768
    unsigned int* Wc1 = (unsigned int*)(ws + 189440);      // 32768
    float* inp   = ws + 484352;                   // 1048576 (both LSTM layers)
    float* h0seq = ws + 1532928;                  // 262144
    float* hfin  = ws + 1795072;                  // 1024

    const int smem_gcn = 142736;
    hipFuncSetAttribute((const void*)gcn_kernel,
                        hipFuncAttributeMaxDynamicSharedMemorySize, smem_gcn);

    setup_kernel<<<449, 512, 0, stream>>>(edges, bih0, bhh0, bih1, bhh1,
                                          bias0, bias1, AbG,
                                          W2, Wt2g, W3, Wt3g,
                                          Whh0, Wc0, Whh1, Wc1,
                                          Wih0, WT0, Wih1, WT1);
    gcn_kernel<<<1024, 512, smem_gcn, stream>>>(snap, scale, shift, W1, b1, b2, b3,
                                                AbG, Wt2g, Wt3g, WT0, bias0, inp);
    scan_kernel<<<BB, 512, 0, stream>>>(inp, Wc0, h0seq, 1);
    proj_kernel<<<GG, 512, 0, stream>>>(h0seq, WT1, bias1, inp);
    scan_kernel<<<BB, 512, 0, stream>>>(inp, Wc1, hfin, 0);
    head_kernel<<<1, 256, 0, stream>>>(hfin, hW1, hb1, hW2, hb2, hW3, hb3, (float*)d_out);
}

// Round 12
// 539.290 us; speedup vs baseline: 1.0177x; 1.0177x over previous
//
#include <hip/hip_runtime.h>
#include <math.h>

// Problem constants
#define NN 118   // nodes
#define EE 372   // edges
#define GG 2048  // B*T
#define DD 128   // hidden
#define TT 256   // seq len
#define BB 8     // batch
#define FD 512   // 4*D

// LDS stride for bf16 matrices (rows 16B-aligned, 2-way-max bank aliasing)
#define XS 136

typedef short bf16x8 __attribute__((ext_vector_type(8)));
typedef float f32x4  __attribute__((ext_vector_type(4)));
typedef _Float16 f16x2 __attribute__((ext_vector_type(2)));

__device__ __forceinline__ float frcp_(float x) { return __builtin_amdgcn_rcpf(x); }
__device__ __forceinline__ float sig_f(float x) { return frcp_(1.0f + __expf(-x)); }
__device__ __forceinline__ float tanh_f(float x) { return 1.0f - 2.0f * frcp_(__expf(2.0f * x) + 1.0f); }
__device__ __forceinline__ float silu_f(float x) { return x * frcp_(1.0f + __expf(-x)); }
__device__ __forceinline__ float siluf_(float x) { return x / (1.0f + expf(-x)); }

// f16-pair dot with fp32 accumulate (v_dot2_f32_f16); scalar fallback.
__device__ __forceinline__ float fdot2_(unsigned int a, unsigned int b, float c) {
#if defined(__has_builtin) && __has_builtin(__builtin_amdgcn_fdot2)
    return __builtin_amdgcn_fdot2(__builtin_bit_cast(f16x2, a),
                                  __builtin_bit_cast(f16x2, b), c, false);
#else
    f16x2 x = __builtin_bit_cast(f16x2, a), y = __builtin_bit_cast(f16x2, b);
    return c + (float)x[0] * (float)y[0] + (float)x[1] * (float)y[1];
#endif
}

// Barrier draining only LDS ops (lgkmcnt), not vmcnt: global stores stay
// fire-and-forget, prefetch loads stay in flight. Safe: all cross-thread data
// flows through LDS (global->VGPR uses get compiler vmcnt waits).
__device__ __forceinline__ void bar_lds() {
    asm volatile("s_waitcnt lgkmcnt(0)\n\ts_barrier" ::: "memory");
}

__device__ __forceinline__ unsigned short f2bf(float x) {
    unsigned int u = __float_as_uint(x);
    unsigned int r = (u + 0x7fffu + ((u >> 16) & 1u)) >> 16;
    return (unsigned short)r;
}
__device__ __forceinline__ float bf2f(unsigned short b) {
    return __uint_as_float(((unsigned int)b) << 16);
}

// ---------------------------------------------------------------------------
// setup: ALL weight-prep fused into one launch (449 blocks x 512 thr):
//   [0,32)    convw W2  -> Wt2g      [32,64)   convw W3  -> Wt3g
//   [64,128)  convh Whh0-> Wc0       [128,192) convh Whh1-> Wc1
//   [192,320) transpose Wih0 -> WT0  [320,448) transpose Wih1 -> WT1
//   448       prep (adjacency + fused biases)
// (round-9 verified version, byte-identical)
// ---------------------------------------------------------------------------
__global__ __launch_bounds__(512) void setup_kernel(
    const int* __restrict__ ei,
    const float* __restrict__ bih0, const float* __restrict__ bhh0,
    const float* __restrict__ bih1, const float* __restrict__ bhh1,
    float* __restrict__ bias0, float* __restrict__ bias1,
    unsigned short* __restrict__ AbG,
    const float* __restrict__ W2, unsigned short* __restrict__ Wt2g,
    const float* __restrict__ W3, unsigned short* __restrict__ Wt3g,
    const float* __restrict__ Whh0, unsigned int* __restrict__ Wc0,
    const float* __restrict__ Whh1, unsigned int* __restrict__ Wc1,
    const float* __restrict__ Wih0, float* __restrict__ WT0,
    const float* __restrict__ Wih1, float* __restrict__ WT1) {
    int blk = blockIdx.x, tid = threadIdx.x;
    if (blk < 64) {
        // convw: W (K=128 x N=128, fp32) -> bf16 [n][k]
        const float* W = (blk < 32) ? W2 : W3;
        unsigned short* out = (blk < 32) ? Wt2g : Wt3g;
        int i = (blk & 31) * 512 + tid;  // 16384 total
        int n = i >> 7, k = i & 127;
        out[i] = f2bf(W[k * DD + n]);
        return;
    }
    if (blk < 192) {
        // convh: W[512][128] (rows r=g*128+d) -> quad-K-split f16 pairs
        // (ROUND-3 LAYOUT, verified): out[(g*16+m)*512 + ((d<<2)|q)]
        const float* W = (blk < 128) ? Whh0 : Whh1;
        unsigned int* out = (blk < 128) ? Wc0 : Wc1;
        int i = ((blk - 64) & 63) * 512 + tid;  // 32768 total
        int pair = i >> 9, jj = i & 511;        // pair = g*16+m, jj = (d<<2)|q
        int g = pair >> 4, m = pair & 15;
        int d = jj >> 2, q = jj & 3;
        const float* row = W + (size_t)(g * 128 + d) * 128 + q * 32 + 2 * m;
        float a = row[0], b = row[1];
        unsigned short lo = __builtin_bit_cast(unsigned short, (_Float16)a);
        unsigned short hi = __builtin_bit_cast(unsigned short, (_Float16)b);
        out[i] = (unsigned int)lo | ((unsigned int)hi << 16);
        return;
    }
    if (blk < 448) {
        // transpose: Wih (512x128) -> WT [k=128][j=512]
        const float* in = (blk < 320) ? Wih0 : Wih1;
        float* out = (blk < 320) ? WT0 : WT1;
        int idx = ((blk - 192) & 127) * 512 + tid;  // 65536 total
        int j = idx >> 7, k = idx & 127;
        out[k * FD + j] = in[idx];
        return;
    }
    // ------------------- prep (block 448) -------------------
    __shared__ int sflag;
    __shared__ int ssrc[EE], sdst[EE];
    __shared__ int scount[NN];
    __shared__ float sinv[NN];
    __shared__ float Adense[NN * NN];  // 55.7 KB
    if (tid == 0) sflag = 0;
    __syncthreads();
    // int64-vs-int32 layout detect (values < 118 -> high words zero if int64)
    for (int i = tid; i < 2 * EE; i += blockDim.x)
        if ((i & 1) && ei[i] != 0) atomicOr(&sflag, 1);
    __syncthreads();
    bool m64 = (sflag == 0);
    for (int e = tid; e < EE; e += blockDim.x) {
        int s, d;
        if (m64) { s = ei[2 * e]; d = ei[2 * EE + 2 * e]; }
        else     { s = ei[e];     d = ei[EE + e]; }
        s = min(max(s, 0), NN - 1); d = min(max(d, 0), NN - 1);
        ssrc[e] = s; sdst[e] = d;
    }
    for (int n = tid; n < NN; n += blockDim.x) scount[n] = 0;
    for (int i = tid; i < NN * NN; i += blockDim.x) Adense[i] = 0.0f;
    __syncthreads();
    for (int e = tid; e < EE; e += blockDim.x) atomicAdd(&scount[sdst[e]], 1);
    __syncthreads();
    for (int n = tid; n < NN; n += blockDim.x) {
        float deg = 1.0f + (float)scount[n];
        sinv[n] = rsqrtf(deg);
        Adense[n * NN + n] = 1.0f / deg;   // self term h*(1/deg)
    }
    __syncthreads();
    for (int e = tid; e < EE; e += blockDim.x)
        atomicAdd(&Adense[sdst[e] * NN + ssrc[e]], sinv[ssrc[e]] * sinv[sdst[e]]);
    __syncthreads();
    for (int i = tid; i < 128 * 128; i += blockDim.x) {
        int r = i >> 7, c = i & 127;
        AbG[i] = (r < NN && c < NN) ? f2bf(Adense[r * NN + c]) : (unsigned short)0;
    }
    for (int j = tid; j < FD; j += blockDim.x) {
        bias0[j] = bih0[j] + bhh0[j];
        bias1[j] = bih1[j] + bhh1[j];
    }
}

// ---------------------------------------------------------------------------
// GCN building blocks (round-3 LDS-staged versions, verified)
// ---------------------------------------------------------------------------
__device__ __forceinline__ void load_m(const unsigned short* __restrict__ src,
                                       unsigned short* __restrict__ dst, int tid) {
    const uint4* s4 = (const uint4*)src;  // 2048 chunks of 16B (8 bf16)
    for (int c = tid; c < 2048; c += 512) {
        int r = c >> 4, k8 = (c & 15) * 8;
        uint4 v = s4[c];
        *(uint4*)(dst + r * XS + k8) = v;
    }
}

// mm1: hS[n=dout][m=node] = (xb[m][k] @ wt[n][k]) packed bf16
__device__ __forceinline__ void mm_xw(const unsigned short* __restrict__ xb,
                                      const unsigned short* __restrict__ wt,
                                      unsigned short* __restrict__ hS, int tid) {
    int lane = tid & 63, w = tid >> 6;
    int lm = lane & 15, lq = lane >> 4;
    int wm = (w & 1) * 64, wn = (w >> 1) * 32;
    f32x4 acc[4][2];
#pragma unroll
    for (int mt = 0; mt < 4; ++mt)
#pragma unroll
        for (int nt = 0; nt < 2; ++nt) acc[mt][nt] = (f32x4){0.f, 0.f, 0.f, 0.f};
#pragma unroll
    for (int kb = 0; kb < 4; ++kb) {
        int ko = kb * 32 + lq * 8;
        bf16x8 b0 = *(const bf16x8*)(wt + (wn + lm) * XS + ko);
        bf16x8 b1 = *(const bf16x8*)(wt + (wn + 16 + lm) * XS + ko);
#pragma unroll
        for (int mt = 0; mt < 4; ++mt) {
            bf16x8 af = *(const bf16x8*)(xb + (wm + mt * 16 + lm) * XS + ko);
            acc[mt][0] = __builtin_amdgcn_mfma_f32_16x16x32_bf16(af, b0, acc[mt][0], 0, 0, 0);
            acc[mt][1] = __builtin_amdgcn_mfma_f32_16x16x32_bf16(af, b1, acc[mt][1], 0, 0, 0);
        }
    }
#pragma unroll
    for (int mt = 0; mt < 4; ++mt)
#pragma unroll
        for (int nt = 0; nt < 2; ++nt) {
            f32x4 a = acc[mt][nt];
            ushort4 pk;
            pk.x = f2bf(a[0]); pk.y = f2bf(a[1]); pk.z = f2bf(a[2]); pk.w = f2bf(a[3]);
            *(ushort4*)(hS + (wn + nt * 16 + lm) * XS + wm + mt * 16 + lq * 4) = pk;
        }
}

// mm2: xb[m=node][n=d] = silu(Ab[m][k] @ hS[n][k] + bias[n]) bf16
__device__ __forceinline__ void mm_agg(const unsigned short* __restrict__ Ab,
                                       const unsigned short* __restrict__ hS,
                                       unsigned short* __restrict__ xb,
                                       float bn0, float bn1, int tid) {
    int lane = tid & 63, w = tid >> 6;
    int lm = lane & 15, lq = lane >> 4;
    int wm = (w & 1) * 64, wn = (w >> 1) * 32;
    f32x4 acc[4][2];
#pragma unroll
    for (int mt = 0; mt < 4; ++mt)
#pragma unroll
        for (int nt = 0; nt < 2; ++nt) acc[mt][nt] = (f32x4){0.f, 0.f, 0.f, 0.f};
#pragma unroll
    for (int kb = 0; kb < 4; ++kb) {
        int ko = kb * 32 + lq * 8;
        bf16x8 b0 = *(const bf16x8*)(hS + (wn + lm) * XS + ko);
        bf16x8 b1 = *(const bf16x8*)(hS + (wn + 16 + lm) * XS + ko);
#pragma unroll
        for (int mt = 0; mt < 4; ++mt) {
            bf16x8 af = *(const bf16x8*)(Ab + (wm + mt * 16 + lm) * XS + ko);
            acc[mt][0] = __builtin_amdgcn_mfma_f32_16x16x32_bf16(af, b0, acc[mt][0], 0, 0, 0);
            acc[mt][1] = __builtin_amdgcn_mfma_f32_16x16x32_bf16(af, b1, acc[mt][1], 0, 0, 0);
        }
    }
#pragma unroll
    for (int mt = 0; mt < 4; ++mt)
#pragma unroll
        for (int nt = 0; nt < 2; ++nt) {
            float bn = nt ? bn1 : bn0;
            int col = wn + nt * 16 + lm;
#pragma unroll
            for (int i = 0; i < 4; ++i) {
                float v = silu_f(acc[mt][nt][i] + bn);
                xb[(wm + mt * 16 + lq * 4 + i) * XS + col] = f2bf(v);
            }
        }
}

// ---------------------------------------------------------------------------
// gcn: round-9 structure (LDS-staged operands, emb output, separate proj --
// the r11 proj-fusion experiment was a net loss and is reverted) with EIGHT
// graphs per block (grid 256 = exactly one block/CU, single residency round):
// Ab load, zero-inits, W1/bias register setup amortized 8x, no partial-round
// scheduling tail. Per-graph loop body byte-identical to r9's.
// ---------------------------------------------------------------------------
__global__ __launch_bounds__(512) void gcn_kernel(
    const float* __restrict__ xg, const float* __restrict__ scale, const float* __restrict__ shift,
    const float* __restrict__ W1, const float* __restrict__ b1,
    const float* __restrict__ b2, const float* __restrict__ b3,
    const unsigned short* __restrict__ AbG,
    const unsigned short* __restrict__ Wt2g, const unsigned short* __restrict__ Wt3g,
    float* __restrict__ emb) {
    extern __shared__ char smem[];
    unsigned short* xb = (unsigned short*)smem;              // 34816 B  [node][d]
    unsigned short* hS = (unsigned short*)(smem + 34816);    // 34816 B  [d][node]
    unsigned short* Ab = (unsigned short*)(smem + 69632);    // 34816 B  [dst][src]
    unsigned short* wt = (unsigned short*)(smem + 104448);   // 34816 B  [dout][din]
    float* xinL  = (float*)(smem + 139264);                  // 354 f
    float* meanS = (float*)(smem + 140688);                  // 512 f (end 142736)
    int tid = threadIdx.x;
    int lane = tid & 63, w = tid >> 6;

    for (int i = tid; i < 2176; i += 512) ((uint4*)hS)[i] = (uint4){0, 0, 0, 0};
    for (int i = tid; i < 170; i += 512) ((uint4*)(xb + NN * XS))[i] = (uint4){0, 0, 0, 0};
    float s0 = scale[0], s1 = scale[1], s2 = scale[2];
    float t0 = shift[0], t1 = shift[1], t2 = shift[2];
    load_m(AbG, Ab, tid);
    int lm = lane & 15;
    int wn = (w >> 1) * 32;
    int n0 = wn + lm, n1 = wn + 16 + lm;
    float b1a = b1[n0], b1b = b1[n1];
    float b2a = b2[n0], b2b = b2[n1];
    float b3a = b3[n0], b3b = b3[n1];
    int dd = lane * 2;
    float2 w10 = *(const float2*)(W1 + dd);
    float2 w11 = *(const float2*)(W1 + DD + dd);
    float2 w12 = *(const float2*)(W1 + 2 * DD + dd);
    for (int gg = 0; gg < 8; ++gg) {
        int g = blockIdx.x * 8 + gg;
        const float* xrow = xg + (size_t)g * (NN * 3);
        for (int i = tid; i < NN * 3; i += 512) {
            int f = i % 3;
            float sc = (f == 0) ? s0 : ((f == 1) ? s1 : s2);
            float sf = (f == 0) ? t0 : ((f == 1) ? t1 : t2);
            xinL[i] = xrow[i] * sc + sf;
        }
        load_m(Wt2g, wt, tid);
        bar_lds();
        for (int k = 0; k < 15; ++k) {
            int n = w + 8 * k;
            if (n >= NN) break;
            float x0 = xinL[n * 3], x1 = xinL[n * 3 + 1], x2 = xinL[n * 3 + 2];
            hS[dd * XS + n]       = f2bf(x0 * w10.x + x1 * w11.x + x2 * w12.x);
            hS[(dd + 1) * XS + n] = f2bf(x0 * w10.y + x1 * w11.y + x2 * w12.y);
        }
        bar_lds();
        mm_agg(Ab, hS, xb, b1a, b1b, tid);   // x1
        bar_lds();
        mm_xw(xb, wt, hS, tid);              // h2
        bar_lds();
        load_m(Wt3g, wt, tid);
        mm_agg(Ab, hS, xb, b2a, b2b, tid);   // x2
        bar_lds();
        mm_xw(xb, wt, hS, tid);              // h3
        bar_lds();
        mm_agg(Ab, hS, xb, b3a, b3b, tid);   // x3
        bar_lds();
        {
            int d = tid & 127, part = tid >> 7;
            int a0 = part * 30;
            int a1 = (a0 + 30 < NN) ? (a0 + 30) : NN;
            float s = 0.f;
            for (int n = a0; n < a1; ++n) s += bf2f(xb[n * XS + d]);
            meanS[part * 128 + d] = s;
        }
        bar_lds();
        if (tid < 128) {
            float s = meanS[tid] + meanS[128 + tid] + meanS[256 + tid] + meanS[384 + tid];
            emb[(size_t)g * DD + tid] = s * (1.0f / (float)NN);
        }
        bar_lds();
    }
}

// ---------------------------------------------------------------------------
// proj: dst[g][j] = bias[j] + sum_k src[g][k] * WT[k][j]
// ---------------------------------------------------------------------------
__global__ __launch_bounds__(512) void proj_kernel(const float* __restrict__ src,
                                                   const float* __restrict__ WT,
                                                   const float* __restrict__ bias,
                                                   float* __restrict__ dst) {
    __shared__ __align__(16) float eL[DD];
    int g = blockIdx.x, tid = threadIdx.x;
    if (tid < DD) eL[tid] = src[(size_t)g * DD + tid];
    __syncthreads();
    float acc = bias[tid];
    const float* wt = WT + tid;
#pragma unroll 8
    for (int k = 0; k < DD; ++k) acc += eL[k] * wt[(size_t)k * FD];
    dst[(size_t)g * FD + tid] = acc;
}

// ---------------------------------------------------------------------------
// LSTM scan v3: QUAD-K-SPLIT (round-3 verified, byte-identical). Thread
// j = (d = j>>2, q = j&3); quad lane q is BOTH the owned gate index AND the
// K-quarter. Each thread reads its 64 B quarter of h (4 x ds_read_b128),
// computes partials for ALL 4 gates over that quarter, 2-step DPP quad
// butterfly (0xB1, 0x4E), 3 cndmask select own gate, branchless activation,
// quad broadcast (0x00/0x55/0xAA/0xFF), redundant c/h update. One barrier
// per step, h double-buffered (512 B LDS).
// ---------------------------------------------------------------------------
__global__ __launch_bounds__(512, 1) void scan_kernel(
    const float* __restrict__ inp,          // [B][T][512] gate-major (bias incl)
    const unsigned int* __restrict__ Wc,    // [pair=g*16+m][j=(d<<2)|q] f16 pairs
    float* __restrict__ hout, int full) {
    __shared__ __align__(16) unsigned short hB[2][DD];  // h as f16, double-buffered
    int b = blockIdx.x, j = threadIdx.x;
    int d = j >> 2, q = j & 3;
    unsigned int wreg[4][16];  // [gate][pair], K-quarter q only
#pragma unroll
    for (int g = 0; g < 4; ++g)
#pragma unroll
        for (int m = 0; m < 16; ++m)
            wreg[g][m] = Wc[(g * 16 + m) * 512 + j];
    // pin: asm-defined values cannot be rematerialized into the loop
#pragma unroll
    for (int g = 0; g < 4; ++g)
#pragma unroll
        for (int m = 0; m < 16; ++m)
            asm volatile("" : "+v"(wreg[g][m]));
    if (j < 128) ((unsigned int*)hB)[j] = 0u;  // zero both buffers (512 B)
    const float* ib = inp + (size_t)b * TT * FD;
    float* hb_ = hout + (size_t)b * (full ? TT * DD : DD);
    int poff = q * DD + d;
    // branchless activation: act = sig(pre*m1)*m1 + c1  (q==2 -> tanh)
    float m1  = (q == 2) ? 2.0f : 1.0f;
    float nm1 = -m1;
    float c1  = 1.0f - m1;
    bool b0 = (q & 1) != 0, b1s = (q & 2) != 0;  // own-gate select bits
    float creg = 0.f;
    float xg0 = ib[poff], xg1 = ib[FD + poff];  // prefetch depth 2
    int p = 0;
    bar_lds();
    for (int t = 0; t < TT; ++t) {
        float xg2 = (t + 2 < TT) ? ib[(size_t)(t + 2) * FD + poff] : 0.f;
        // each quad lane reads its own 64 B K-quarter (4 chunks)
        const uint4* h4 = (const uint4*)(hB[p]) + q * 4;
        float p0 = 0.f, p1 = 0.f, p2 = 0.f, p3 = 0.f;
#pragma unroll
        for (int c = 0; c < 4; ++c) {
            uint4 hv = h4[c];
            p0 = fdot2_(wreg[0][4 * c + 0], hv.x, p0);
            p1 = fdot2_(wreg[1][4 * c + 0], hv.x, p1);
            p2 = fdot2_(wreg[2][4 * c + 0], hv.x, p2);
            p3 = fdot2_(wreg[3][4 * c + 0], hv.x, p3);
            p0 = fdot2_(wreg[0][4 * c + 1], hv.y, p0);
            p1 = fdot2_(wreg[1][4 * c + 1], hv.y, p1);
            p2 = fdot2_(wreg[2][4 * c + 1], hv.y, p2);
            p3 = fdot2_(wreg[3][4 * c + 1], hv.y, p3);
            p0 = fdot2_(wreg[0][4 * c + 2], hv.z, p0);
            p1 = fdot2_(wreg[1][4 * c + 2], hv.z, p1);
            p2 = fdot2_(wreg[2][4 * c + 2], hv.z, p2);
            p3 = fdot2_(wreg[3][4 * c + 2], hv.z, p3);
            p0 = fdot2_(wreg[0][4 * c + 3], hv.w, p0);
            p1 = fdot2_(wreg[1][4 * c + 3], hv.w, p1);
            p2 = fdot2_(wreg[2][4 * c + 3], hv.w, p2);
            p3 = fdot2_(wreg[3][4 * c + 3], hv.w, p3);
        }
        // quad butterfly: sum the 4 K-quarter partials per gate
#define DPPADD(pv, ctrl) { \
            float _t = __int_as_float(__builtin_amdgcn_update_dpp( \
                0, __float_as_int(pv), ctrl, 0xF, 0xF, true)); \
            pv += _t; }
        DPPADD(p0, 0xB1) DPPADD(p1, 0xB1) DPPADD(p2, 0xB1) DPPADD(p3, 0xB1)
        DPPADD(p0, 0x4E) DPPADD(p1, 0x4E) DPPADD(p2, 0x4E) DPPADD(p3, 0x4E)
#undef DPPADD
        // select own gate (q) and activate
        float s01 = b0 ? p1 : p0;
        float s23 = b0 ? p3 : p2;
        float own = b1s ? s23 : s01;
        float pre = own + xg0;
        float act = frcp_(1.0f + __expf(pre * nm1)) * m1 + c1;
        // quad broadcast: lane k of each quad -> all quad lanes (VALU DPP)
        int ai = __float_as_int(act);
        float iv = __int_as_float(__builtin_amdgcn_update_dpp(0, ai, 0x00, 0xF, 0xF, true));
        float fv = __int_as_float(__builtin_amdgcn_update_dpp(0, ai, 0x55, 0xF, 0xF, true));
        float gv = __int_as_float(__builtin_amdgcn_update_dpp(0, ai, 0xAA, 0xF, 0xF, true));
        float ov = __int_as_float(__builtin_amdgcn_update_dpp(0, ai, 0xFF, 0xF, 0xF, true));
        float cn = fv * creg + iv * gv;
        creg = cn;
        float hn = ov * tanh_f(cn);
        if (q == 0) {
            ((_Float16*)hB[p ^ 1])[d] = (_Float16)hn;
            if (full) {
                hb_[t * DD + d] = hn;                 // fire-and-forget
            } else if (t == TT - 1) {
                hb_[d] = hn;
            }
        }
        xg0 = xg1; xg1 = xg2;
        p ^= 1;
        bar_lds();
    }
}

// ---------------------------------------------------------------------------
// head MLP on final hidden state. 1 block.
// ---------------------------------------------------------------------------
__global__ void head_kernel(const float* __restrict__ hfin,
                            const float* __restrict__ hW1, const float* __restrict__ hb1,
                            const float* __restrict__ hW2, const float* __restrict__ hb2,
                            const float* __restrict__ hW3, const float* __restrict__ hb3,
                            float* __restrict__ out) {
    __shared__ float fh[BB * DD];
    __shared__ float y1[BB * DD];
    __shared__ float y2[BB * 64];
    int tid = threadIdx.x;
    for (int i = tid; i < BB * DD; i += 256) fh[i] = hfin[i];
    __syncthreads();
    for (int i = tid; i < BB * DD; i += 256) {
        int bb = i >> 7, jj = i & 127;
        float acc = hb1[jj];
        for (int k = 0; k < DD; ++k) acc += fh[(bb << 7) + k] * hW1[(k << 7) + jj];
        y1[i] = siluf_(acc);
    }
    __syncthreads();
    for (int i = tid; i < BB * 64; i += 256) {
        int bb = i >> 6, jj = i & 63;
        float acc = hb2[jj];
        for (int k = 0; k < DD; ++k) acc += y1[(bb << 7) + k] * hW2[(k << 6) + jj];
        y2[i] = siluf_(acc);
    }
    __syncthreads();
    if (tid < BB * 2) {
        int bb = tid >> 1, m = tid & 1;
        float acc = hb3[m];
        for (int k = 0; k < 64; ++k) acc += y2[(bb << 6) + k] * hW3[k * 2 + m];
        float sp = fmaxf(acc, 0.f) + log1pf(expf(-fabsf(acc)));
        out[tid] = sp + 1e-6f;
    }
}

// ---------------------------------------------------------------------------
extern "C" void kernel_launch(void* const* d_in, const int* in_sizes, int n_in,
                              void* d_out, int out_size, void* d_ws, size_t ws_size,
                              hipStream_t stream) {
    const float* snap  = (const float*)d_in[0];
    const int*   edges = (const int*)d_in[1];
    const float* scale = (const float*)d_in[2];
    const float* shift = (const float*)d_in[3];
    const float* W1 = (const float*)d_in[4];
    const float* b1 = (const float*)d_in[5];
    const float* W2 = (const float*)d_in[6];
    const float* b2 = (const float*)d_in[7];
    const float* W3 = (const float*)d_in[8];
    const float* b3 = (const float*)d_in[9];
    const float* Wih0 = (const float*)d_in[10];
    const float* Whh0 = (const float*)d_in[11];
    const float* bih0 = (const float*)d_in[12];
    const float* bhh0 = (const float*)d_in[13];
    const float* Wih1 = (const float*)d_in[14];
    const float* Whh1 = (const float*)d_in[15];
    const float* bih1 = (const float*)d_in[16];
    const float* bhh1 = (const float*)d_in[17];
    const float* hW1 = (const float*)d_in[18];
    const float* hb1 = (const float*)d_in[19];
    const float* hW2 = (const float*)d_in[20];
    const float* hb2 = (const float*)d_in[21];
    const float* hW3 = (const float*)d_in[22];
    const float* hb3 = (const float*)d_in[23];

    // workspace carve (float indices); ~7.2 MB  (round-9 layout, verified)
    float* ws = (float*)d_ws;
    float* bias0 = ws + 0;                        // 512
    float* bias1 = ws + 512;                      // 512
    unsigned short* AbG  = (unsigned short*)(ws + 1024);   // 8192 f
    unsigned short* Wt2g = (unsigned short*)(ws + 9216);   // 8192 f
    unsigned short* Wt3g = (unsigned short*)(ws + 17408);  // 8192 f
    float* WT0 = ws + 25600;                      // 65536
    float* WT1 = ws + 91136;                      // 65536
    unsigned int* Wc0 = (unsigned int*)(ws + 156672);      // 32768
    unsigned int* Wc1 = (unsigned int*)(ws + 189440);      // 32768
    float* emb   = ws + 222208;                   // 262144
    float* inp   = ws + 484352;                   // 1048576 (both LSTM layers)
    float* h0seq = ws + 1532928;                  // 262144
    float* hfin  = ws + 1795072;                  // 1024

    const int smem_gcn = 142736;
    hipFuncSetAttribute((const void*)gcn_kernel,
                        hipFuncAttributeMaxDynamicSharedMemorySize, smem_gcn);

    setup_kernel<<<449, 512, 0, stream>>>(edges, bih0, bhh0, bih1, bhh1,
                                          bias0, bias1, AbG,
                                          W2, Wt2g, W3, Wt3g,
                                          Whh0, Wc0, Whh1, Wc1,
                                          Wih0, WT0, Wih1, WT1);
    gcn_kernel<<<256, 512, smem_gcn, stream>>>(snap, scale, shift, W1, b1, b2, b3,
                                               AbG, Wt2g, Wt3g, emb);
    proj_kernel<<<GG, 512, 0, stream>>>(emb, WT0, bias0, inp);
    scan_kernel<<<BB, 512, 0, stream>>>(inp, Wc0, h0seq, 1);
    proj_kernel<<<GG, 512, 0, stream>>>(h0seq, WT1, bias1, inp);
    scan_kernel<<<BB, 512, 0, stream>>>(inp, Wc1, hfin, 0);
    head_kernel<<<1, 256, 0, stream>>>(hfin, hW1, hb1, hW2, hb2, hW3, hb3, (float*)d_out);
}